// Round 1
// baseline (275.757 us; speedup 1.0000x reference)
//
#include <hip/hip_runtime.h>
#include <hip/hip_bf16.h>

typedef unsigned short u16;
typedef unsigned int   u32;

#define MM 8192
#define DD 128

using short8 = __attribute__((ext_vector_type(8))) short;
using f32x4  = __attribute__((ext_vector_type(4))) float;

__device__ __forceinline__ u16 f2bf(float f) {
  u32 u = __float_as_uint(f);
  u32 r = u + 0x7fffu + ((u >> 16) & 1u);   // RNE
  return (u16)(r >> 16);
}

// One wave per row: bf16 conversion + squared norms.
__global__ __launch_bounds__(256) void convert_kernel(
    const float* __restrict__ x, const float* __restrict__ y,
    u16* __restrict__ xb, u16* __restrict__ yb,
    float* __restrict__ sqx, float* __restrict__ sqy)
{
  const int wid  = threadIdx.x >> 6;
  const int lane = threadIdx.x & 63;
  const int row  = blockIdx.x * 4 + wid;
  const float2 vx = *(const float2*)(x + (size_t)row * DD + lane * 2);
  const float2 vy = *(const float2*)(y + (size_t)row * DD + lane * 2);
  float sx = vx.x * vx.x + vx.y * vx.y;
  float sy = vy.x * vy.x + vy.y * vy.y;
  #pragma unroll
  for (int off = 1; off < 64; off <<= 1) {
    sx += __shfl_xor(sx, off, 64);
    sy += __shfl_xor(sy, off, 64);
  }
  u32 px = (u32)f2bf(vx.x) | ((u32)f2bf(vx.y) << 16);
  u32 py = (u32)f2bf(vy.x) | ((u32)f2bf(vy.y) << 16);
  *(u32*)(xb + (size_t)row * DD + lane * 2) = px;
  *(u32*)(yb + (size_t)row * DD + lane * 2) = py;
  if (lane == 0) { sqx[row] = sx; sqy[row] = sy; }
}

// 128x128 output tile per block; 4 waves in 2x2, each wave 64x64.
// For each 16x16 subtile: 4 MFMA (K=128) for x-dots + 4 for y-dots,
// then epilogue: K=exp(2*dot - |r|^2 - |c|^2), L likewise, accumulate
// P += K*L, row sums of K into s[], of L into t[]. Diagonal overridden
// to exactly 1 (bf16 dot is not exact there; off-diagonals all underflow).
__global__ __launch_bounds__(256, 2) void hsic_pair_kernel(
    const u16* __restrict__ xb, const u16* __restrict__ yb,
    const float* __restrict__ sqx, const float* __restrict__ sqy,
    float* __restrict__ s, float* __restrict__ t, float* __restrict__ P)
{
  const int i0   = blockIdx.y * 128;
  const int j0   = blockIdx.x * 128;
  const int tid  = threadIdx.x;
  const int wid  = tid >> 6;
  const int lane = tid & 63;
  const int wr   = wid >> 1;
  const int wc   = wid & 1;
  const int g    = lane >> 4;   // 0..3  (K-chunk for A/B frags, row-group for acc)
  const int c    = lane & 15;   // 0..15 (row for A-frag, col for B-frag/acc)

  const int ri = i0 + wr * 64;
  const int cj = j0 + wc * 64;

  // Persistent B fragments for this wave's 64 columns (x and y).
  short8 bx[4][4], by[4][4];
  float sqxc[4], sqyc[4];
  #pragma unroll
  for (int cs = 0; cs < 4; ++cs) {
    const int crow = cj + cs * 16 + c;     // X/Y row supplying this column
    const u16* pxc = xb + (size_t)crow * DD + g * 8;
    const u16* pyc = yb + (size_t)crow * DD + g * 8;
    #pragma unroll
    for (int kk = 0; kk < 4; ++kk) {
      bx[cs][kk] = *(const short8*)(pxc + kk * 32);
      by[cs][kk] = *(const short8*)(pyc + kk * 32);
    }
    sqxc[cs] = sqx[crow];
    sqyc[cs] = sqy[crow];
  }

  float p_acc = 0.f;

  #pragma unroll
  for (int rs = 0; rs < 4; ++rs) {
    const int arow = ri + rs * 16 + c;     // A-frag row (lane&15)
    const u16* pax = xb + (size_t)arow * DD + g * 8;
    const u16* pay = yb + (size_t)arow * DD + g * 8;
    short8 ax[4], ay[4];
    #pragma unroll
    for (int kk = 0; kk < 4; ++kk) {
      ax[kk] = *(const short8*)(pax + kk * 32);
      ay[kk] = *(const short8*)(pay + kk * 32);
    }
    // acc rows for this lane: ri + rs*16 + g*4 + tt
    float sqxr[4], sqyr[4];
    #pragma unroll
    for (int tt = 0; tt < 4; ++tt) {
      const int rr = ri + rs * 16 + g * 4 + tt;
      sqxr[tt] = sqx[rr];
      sqyr[tt] = sqy[rr];
    }

    float s_acc[4] = {0.f, 0.f, 0.f, 0.f};
    float t_acc[4] = {0.f, 0.f, 0.f, 0.f};

    #pragma unroll
    for (int cs = 0; cs < 4; ++cs) {
      f32x4 accx = {0.f, 0.f, 0.f, 0.f};
      f32x4 accy = {0.f, 0.f, 0.f, 0.f};
      #pragma unroll
      for (int kk = 0; kk < 4; ++kk) {
        accx = __builtin_amdgcn_mfma_f32_16x16x32_bf16(ax[kk], bx[cs][kk], accx, 0, 0, 0);
        accy = __builtin_amdgcn_mfma_f32_16x16x32_bf16(ay[kk], by[cs][kk], accy, 0, 0, 0);
      }
      const int gc = cj + cs * 16 + c;
      #pragma unroll
      for (int tt = 0; tt < 4; ++tt) {
        const int gr = ri + rs * 16 + g * 4 + tt;
        float kx, ly;
        if (gr == gc) {
          kx = 1.f; ly = 1.f;   // exact diagonal
        } else {
          kx = __expf(2.f * accx[tt] - sqxr[tt] - sqxc[cs]);
          ly = __expf(2.f * accy[tt] - sqyr[tt] - sqyc[cs]);
        }
        p_acc    += kx * ly;
        s_acc[tt] += kx;
        t_acc[tt] += ly;
      }
    }

    // Reduce row sums across the 16 lanes sharing g (they hold the 16 cols).
    #pragma unroll
    for (int tt = 0; tt < 4; ++tt) {
      float sv = s_acc[tt];
      float tv = t_acc[tt];
      #pragma unroll
      for (int off = 1; off < 16; off <<= 1) {
        sv += __shfl_xor(sv, off, 64);
        tv += __shfl_xor(tv, off, 64);
      }
      if (c == 0) {
        const int gr = ri + rs * 16 + g * 4 + tt;
        atomicAdd(&s[gr], sv);
        atomicAdd(&t[gr], tv);
      }
    }
  }

  // Block-reduce P.
  #pragma unroll
  for (int off = 1; off < 64; off <<= 1) p_acc += __shfl_xor(p_acc, off, 64);
  __shared__ float red[4];
  if (lane == 0) red[wid] = p_acc;
  __syncthreads();
  if (tid == 0) atomicAdd(P, red[0] + red[1] + red[2] + red[3]);
}

__global__ __launch_bounds__(256) void finalize_kernel(
    const float* __restrict__ s, const float* __restrict__ t,
    const float* __restrict__ P, float* __restrict__ out)
{
  const int tid = threadIdx.x;
  float sk = 0.f, sl = 0.f, cc = 0.f;
  for (int i = tid; i < MM; i += 256) {
    const float a = s[i], b = t[i];
    sk += a; sl += b; cc += a * b;
  }
  #pragma unroll
  for (int off = 1; off < 64; off <<= 1) {
    sk += __shfl_xor(sk, off, 64);
    sl += __shfl_xor(sl, off, 64);
    cc += __shfl_xor(cc, off, 64);
  }
  __shared__ float rs_[4], rl_[4], rc_[4];
  const int wid = tid >> 6, lane = tid & 63;
  if (lane == 0) { rs_[wid] = sk; rl_[wid] = sl; rc_[wid] = cc; }
  __syncthreads();
  if (tid == 0) {
    const double SK = (double)rs_[0] + rs_[1] + rs_[2] + rs_[3];
    const double SL = (double)rl_[0] + rl_[1] + rl_[2] + rl_[3];
    const double C  = (double)rc_[0] + rc_[1] + rc_[2] + rc_[3];
    const double m  = (double)MM;
    const double num = (double)P[0] - (2.0 / m) * C + (SK * SL) / (m * m);
    out[0] = (float)(num / ((m - 1.0) * (m - 1.0)));
  }
}

extern "C" void kernel_launch(void* const* d_in, const int* in_sizes, int n_in,
                              void* d_out, int out_size, void* d_ws, size_t ws_size,
                              hipStream_t stream) {
  const float* x = (const float*)d_in[0];
  const float* y = (const float*)d_in[1];

  char* ws = (char*)d_ws;
  u16*   xb  = (u16*)ws;                                   // 2 MB
  u16*   yb  = (u16*)(ws + (size_t)2 * 1024 * 1024);       // 2 MB
  float* sqx = (float*)(ws + (size_t)4 * 1024 * 1024);     // 32 KB
  float* sqy = sqx + MM;                                   // 32 KB
  float* s   = sqy + MM;                                   // 32 KB
  float* t   = s + MM;                                     // 32 KB
  float* P   = t + MM;                                     // 4 B

  // zero s, t, P (contiguous)
  hipMemsetAsync(s, 0, (size_t)(2 * MM + 1) * sizeof(float), stream);

  convert_kernel<<<MM / 4, 256, 0, stream>>>(x, y, xb, yb, sqx, sqy);

  dim3 grid(MM / 128, MM / 128);
  hsic_pair_kernel<<<grid, 256, 0, stream>>>(xb, yb, sqx, sqy, s, t, P);

  finalize_kernel<<<1, 256, 0, stream>>>(s, t, P, (float*)d_out);
}